// Round 6
// baseline (1979.990 us; speedup 1.0000x reference)
//
#include <hip/hip_runtime.h>

namespace {

constexpr int kNU = 100000;
constexpr int kNI = 50000;
constexpr int kN  = 150000;
constexpr int kH  = 128;
constexpr int kEP = 2000000;
constexpr int kEN = 1000000;
constexpr int kL  = 2;

constexpr int SCAN_BS = 256;
constexpr int SCAN_IT = 4;
constexpr int SCAN_TILE = SCAN_BS * SCAN_IT;

constexpr int kAP = 66;  // padded A-chunk row stride (2-way bank alias = free)

// ---- degree counting ----
__global__ void count_kernel(const int* __restrict__ dst, int E, int* __restrict__ deg) {
  int t = blockIdx.x * blockDim.x + threadIdx.x;
  if (t < E) atomicAdd(&deg[dst[t]], 1);
}

__global__ void inv_kernel(const int* __restrict__ deg, float* __restrict__ inv, int n) {
  int t = blockIdx.x * blockDim.x + threadIdx.x;
  if (t < n) inv[t] = 1.0f / fmaxf((float)deg[t], 1.0f);
}

// ---- 3-phase exclusive scan ----
__global__ void scan_partial(const int* __restrict__ deg, int n,
                             int* __restrict__ off, int* __restrict__ sums) {
  __shared__ int sh[SCAN_BS];
  const int t = threadIdx.x;
  const int base = blockIdx.x * SCAN_TILE;
  int v[SCAN_IT];
  int run = 0;
#pragma unroll
  for (int j = 0; j < SCAN_IT; ++j) {
    int idx = base + t * SCAN_IT + j;
    v[j] = (idx < n) ? deg[idx] : 0;
    run += v[j];
  }
  sh[t] = run;
  __syncthreads();
  for (int d = 1; d < SCAN_BS; d <<= 1) {
    int x = (t >= d) ? sh[t - d] : 0;
    __syncthreads();
    sh[t] += x;
    __syncthreads();
  }
  int acc = sh[t] - run;
  if (t == SCAN_BS - 1) sums[blockIdx.x] = sh[t];
#pragma unroll
  for (int j = 0; j < SCAN_IT; ++j) {
    int idx = base + t * SCAN_IT + j;
    acc += v[j];
    if (idx < n) off[idx + 1] = acc;
  }
}

__global__ void scan_sums(int* __restrict__ sums, int nb) {
  __shared__ int sh[SCAN_BS];
  const int t = threadIdx.x;
  int v = (t < nb) ? sums[t] : 0;
  sh[t] = v;
  __syncthreads();
  for (int d = 1; d < SCAN_BS; d <<= 1) {
    int x = (t >= d) ? sh[t - d] : 0;
    __syncthreads();
    sh[t] += x;
    __syncthreads();
  }
  if (t < nb) sums[t] = sh[t] - v;
}

__global__ void scan_add(int* __restrict__ off, int n, const int* __restrict__ sums) {
  int t = blockIdx.x * blockDim.x + threadIdx.x;
  if (t == 0) off[0] = 0;
  if (t < n) off[t + 1] += sums[t / SCAN_TILE];
}

// ---- CSR fill ----
__global__ void fill_kernel(const int* __restrict__ src, const int* __restrict__ dst, int E,
                            int* __restrict__ cursor, int* __restrict__ eids) {
  int t = blockIdx.x * blockDim.x + threadIdx.x;
  if (t < E) {
    int p = atomicAdd(&cursor[dst[t]], 1);
    eids[p] = src[t];
  }
}

// ---- CSR gather-mean (full 128-wide) ----
template <bool SPLIT>
__global__ __launch_bounds__(256) void agg_csr(
    const int* __restrict__ off, const int* __restrict__ eids,
    const float* __restrict__ inv,
    const float* __restrict__ zu, const float* __restrict__ zi,
    float* __restrict__ aggOut) {
  const int g = threadIdx.x >> 5;
  const int lane = threadIdx.x & 31;
  const int row = blockIdx.x * 8 + g;
  if (row >= kN) return;
  const int s = off[row], e = off[row + 1];
  float4 acc = make_float4(0.f, 0.f, 0.f, 0.f);
  int i = s;
  for (; i + 2 <= e; i += 2) {
    int s0 = eids[i], s1 = eids[i + 1];
    const float* r0;
    const float* r1;
    if (SPLIT) {
      r0 = (s0 < kNU) ? zu + (size_t)s0 * kH : zi + (size_t)(s0 - kNU) * kH;
      r1 = (s1 < kNU) ? zu + (size_t)s1 * kH : zi + (size_t)(s1 - kNU) * kH;
    } else {
      r0 = zu + (size_t)s0 * kH;
      r1 = zu + (size_t)s1 * kH;
    }
    float4 v0 = *reinterpret_cast<const float4*>(r0 + lane * 4);
    float4 v1 = *reinterpret_cast<const float4*>(r1 + lane * 4);
    acc.x += v0.x + v1.x; acc.y += v0.y + v1.y;
    acc.z += v0.z + v1.z; acc.w += v0.w + v1.w;
  }
  if (i < e) {
    int s0 = eids[i];
    const float* r0;
    if (SPLIT) r0 = (s0 < kNU) ? zu + (size_t)s0 * kH : zi + (size_t)(s0 - kNU) * kH;
    else r0 = zu + (size_t)s0 * kH;
    float4 v0 = *reinterpret_cast<const float4*>(r0 + lane * 4);
    acc.x += v0.x; acc.y += v0.y; acc.z += v0.z; acc.w += v0.w;
  }
  const float sc = inv[row];
  float4 r = make_float4(acc.x * sc, acc.y * sc, acc.z * sc, acc.w * sc);
  *reinterpret_cast<float4*>(aggOut + (size_t)row * kH + lane * 4) = r;
}

// ---- gemm2 helpers ----
// Stage a 128-row x 64-col A panel into LDS [128][kAP].
template <bool SPLIT>
__device__ inline void stage_A(float* __restrict__ at, int rb0,
                               const float* __restrict__ Pu,
                               const float* __restrict__ Pi,
                               int coloff, int tid) {
#pragma unroll
  for (int i = tid; i < 128 * 16; i += 256) {
    int row = i >> 4;
    int c4 = (i & 15) << 2;
    int rr = rb0 + row;
    if (rr >= kN) rr = kN - 1;
    const float* s;
    if (SPLIT) s = (rr < kNU) ? Pu + (size_t)rr * kH : Pi + (size_t)(rr - kNU) * kH;
    else       s = Pu + (size_t)rr * kH;
    *reinterpret_cast<float4*>(at + row * kAP + c4) =
        *reinterpret_cast<const float4*>(s + coloff + c4);
  }
}

// Stage a 64x64 W chunk (row-major, k-major) into LDS.
__device__ inline void stage_W(float* __restrict__ wc, const float* __restrict__ W,
                               int tid) {
  const float4* s = reinterpret_cast<const float4*>(W);
  float4* d = reinterpret_cast<float4*>(wc);
#pragma unroll
  for (int i = tid; i < 64 * 16; i += 256) d[i] = s[i];
}

// acc[r][c] += sum_k A[r0+r][k] * W[k][c0+c], k in [0,64)
__device__ inline void compute_chunk(const float* __restrict__ at,
                                     const float* __restrict__ wc,
                                     int r0, int c0, float4* __restrict__ acc) {
#pragma unroll 2
  for (int kc = 0; kc < 64; kc += 4) {
    float4 av[8];
#pragma unroll
    for (int r = 0; r < 8; ++r)
      av[r] = *reinterpret_cast<const float4*>(at + (r0 + r) * kAP + kc);
    float4 wv[4];
#pragma unroll
    for (int j = 0; j < 4; ++j)
      wv[j] = *reinterpret_cast<const float4*>(wc + (kc + j) * 64 + c0);
#pragma unroll
    for (int r = 0; r < 8; ++r) {
      float4 a = av[r];
      acc[r].x = fmaf(a.w, wv[3].x, fmaf(a.z, wv[2].x, fmaf(a.y, wv[1].x, fmaf(a.x, wv[0].x, acc[r].x))));
      acc[r].y = fmaf(a.w, wv[3].y, fmaf(a.z, wv[2].y, fmaf(a.y, wv[1].y, fmaf(a.x, wv[0].y, acc[r].y))));
      acc[r].z = fmaf(a.w, wv[3].z, fmaf(a.z, wv[2].z, fmaf(a.y, wv[1].z, fmaf(a.x, wv[0].z, acc[r].z))));
      acc[r].w = fmaf(a.w, wv[3].w, fmaf(a.z, wv[2].w, fmaf(a.y, wv[1].w, fmaf(a.x, wv[0].w, acc[r].w))));
    }
  }
}

// ---- fused GEMM half-layer, 2-D register tiling ----
// out[:, ooff:+64] = relu( P1[:, o1:+64] @ W1[0:64,:] + P2[:, o2:+64] @ W1[64:128,:]
//                          + X[:, oz:+K2] @ W2 + bias )
// Block: 128 rows x 64 cols; 256 threads; thread = 8 rows x 4 cols (float4 acc[8]).
// K processed in 64-wide panel chunks; A-chunk[128][66] + W-chunk[64][64] staged
// per chunk (50KB LDS -> 3 blocks/CU). 1.5 B LDS per FMA (vs 4.5 before).
// In-place safe: X reads complete (barrier) before any out writes.
template <int K2, bool SPLITX>
__global__ __launch_bounds__(256, 3) void gemm2(
    const float* __restrict__ P1, int o1,
    const float* __restrict__ P2, int o2,
    const float* __restrict__ W1,   // 128 x 64
    const float* __restrict__ Xu, const float* __restrict__ Xi, int oz,
    const float* __restrict__ W2,   // K2 x 64
    const float* __restrict__ bias,
    float* __restrict__ out, int ooff) {
  __shared__ float at[128 * kAP];  // 33792 B
  __shared__ float wc[64 * 64];    // 16384 B
  const int tid = threadIdx.x;
  const int rb0 = blockIdx.x * 128;
  const int c0 = (tid & 15) << 2;
  const int r0 = (tid >> 4) << 3;

  float4 acc[8];
  {
    float4 b4 = *reinterpret_cast<const float4*>(bias + c0);
#pragma unroll
    for (int r = 0; r < 8; ++r) acc[r] = b4;
  }

  // chunk 0: P1 slice x W1[0:64]
  stage_A<false>(at, rb0, P1, nullptr, o1, tid);
  stage_W(wc, W1, tid);
  __syncthreads();
  compute_chunk(at, wc, r0, c0, acc);
  __syncthreads();

  // chunk 1: P2 slice x W1[64:128]
  stage_A<false>(at, rb0, P2, nullptr, o2, tid);
  stage_W(wc, W1 + 64 * 64, tid);
  __syncthreads();
  compute_chunk(at, wc, r0, c0, acc);
  __syncthreads();

  // chunk 2: X[:, oz:+64] x W2[0:64]
  stage_A<SPLITX>(at, rb0, Xu, Xi, oz, tid);
  stage_W(wc, W2, tid);
  __syncthreads();
  compute_chunk(at, wc, r0, c0, acc);

  if constexpr (K2 == 128) {
    __syncthreads();
    stage_A<SPLITX>(at, rb0, Xu, Xi, oz + 64, tid);
    stage_W(wc, W2 + 64 * 64, tid);
    __syncthreads();
    compute_chunk(at, wc, r0, c0, acc);
  }

  // all global X reads completed before the last barrier -> in-place safe
#pragma unroll
  for (int r = 0; r < 8; ++r) {
    int rr = rb0 + r0 + r;
    if (rr < kN) {
      float4 v = acc[r];
      v.x = fmaxf(v.x, 0.0f); v.y = fmaxf(v.y, 0.0f);
      v.z = fmaxf(v.z, 0.0f); v.w = fmaxf(v.w, 0.0f);
      *reinterpret_cast<float4*>(out + (size_t)rr * kH + ooff + c0) = v;
    }
  }
}

inline float* align16(void* p) {
  return (float*)(((uintptr_t)p + 15) & ~(uintptr_t)15);
}

}  // namespace

extern "C" void kernel_launch(void* const* d_in, const int* in_sizes, int n_in,
                              void* d_out, int out_size, void* d_ws, size_t ws_size,
                              hipStream_t stream) {
  const int*   pos     = (const int*)d_in[0];
  const int*   neg     = (const int*)d_in[1];
  const float* users   = (const float*)d_in[2];
  const float* items   = (const float*)d_in[3];
  const float* c1_wpl  = (const float*)d_in[4];
  const float* c1_wpr  = (const float*)d_in[5];
  const float* c1_bpr  = (const float*)d_in[6];
  const float* c1_wnl  = (const float*)d_in[7];
  const float* c1_wnr  = (const float*)d_in[8];
  const float* c1_bnr  = (const float*)d_in[9];
  const float* cw_pl   = (const float*)d_in[10];
  const float* cw_pr   = (const float*)d_in[11];
  const float* cb_pr   = (const float*)d_in[12];
  const float* cw_nl   = (const float*)d_in[13];
  const float* cw_nr   = (const float*)d_in[14];
  const float* cb_nr   = (const float*)d_in[15];
  float* out = (float*)d_out;

  const int* pos_src = pos;
  const int* pos_dst = pos + kEP;
  const int* neg_src = neg;
  const int* neg_dst = neg + kEN;

  // ---- workspace layout ----
  float* invp = (float*)d_ws;
  float* invn = invp + kN;
  int* degp   = (int*)(invn + kN);
  int* degn   = degp + kN;
  int* offp   = degn + kN;
  int* offn   = offp + kN + 1;
  int* sums   = offn + kN + 1;
  int* eidp   = sums + 256;
  int* eidn   = eidp + kEP;
  float* aggP = align16(eidn + kEN);
  float* aggN = aggP + (size_t)kN * kH;
  const size_t need = (size_t)((char*)(aggN + (size_t)kN * kH) - (char*)d_ws);
  if (ws_size < need) return;

  const int nbP = (kN + SCAN_TILE - 1) / SCAN_TILE;

  // ---- degree counts + inverses ----
  hipMemsetAsync(degp, 0, (size_t)2 * kN * sizeof(int), stream);
  count_kernel<<<(kEP + 255) / 256, 256, 0, stream>>>(pos_dst, kEP, degp);
  count_kernel<<<(kEN + 255) / 256, 256, 0, stream>>>(neg_dst, kEN, degn);
  inv_kernel<<<(kN + 255) / 256, 256, 0, stream>>>(degp, invp, kN);
  inv_kernel<<<(kN + 255) / 256, 256, 0, stream>>>(degn, invn, kN);

  // ---- CSR build (pos) ----
  scan_partial<<<nbP, SCAN_BS, 0, stream>>>(degp, kN, offp, sums);
  scan_sums<<<1, SCAN_BS, 0, stream>>>(sums, nbP);
  scan_add<<<(kN + 255) / 256, 256, 0, stream>>>(offp, kN, sums);
  hipMemcpyAsync(degp, offp, (size_t)kN * sizeof(int), hipMemcpyDeviceToDevice, stream);
  fill_kernel<<<(kEP + 255) / 256, 256, 0, stream>>>(pos_src, pos_dst, kEP, degp, eidp);

  // ---- CSR build (neg) ----
  scan_partial<<<nbP, SCAN_BS, 0, stream>>>(degn, kN, offn, sums);
  scan_sums<<<1, SCAN_BS, 0, stream>>>(sums, nbP);
  scan_add<<<(kN + 255) / 256, 256, 0, stream>>>(offn, kN, sums);
  hipMemcpyAsync(degn, offn, (size_t)kN * sizeof(int), hipMemcpyDeviceToDevice, stream);
  fill_kernel<<<(kEN + 255) / 256, 256, 0, stream>>>(neg_src, neg_dst, kEN, degn, eidn);

  const int gA = (kN + 7) / 8;
  const int gG = (kN + 127) / 128;

  // ---- layer 1 ----
  agg_csr<true><<<gA, 256, 0, stream>>>(offp, eidp, invp, users, items, aggP);
  agg_csr<true><<<gA, 256, 0, stream>>>(offn, eidn, invn, users, items, aggN);
  gemm2<128, true><<<gG, 256, 0, stream>>>(aggP, 0, aggP, 64, c1_wpl,
                                           users, items, 0, c1_wpr, c1_bpr, out, 0);
  gemm2<128, true><<<gG, 256, 0, stream>>>(aggN, 0, aggN, 64, c1_wnl,
                                           users, items, 0, c1_wnr, c1_bnr, out, 64);

  // ---- inner layers: z lives in d_out, updated in place ----
  for (int l = 0; l < kL; ++l) {
    const float* wpl = cw_pl + (size_t)l * kH * 64;
    const float* wpr = cw_pr + (size_t)l * 64 * 64;
    const float* bpr = cb_pr + (size_t)l * 64;
    const float* wnl = cw_nl + (size_t)l * kH * 64;
    const float* wnr = cw_nr + (size_t)l * 64 * 64;
    const float* bnr = cb_nr + (size_t)l * 64;

    // aggP = mean_p(z) = [a_pp | a_np]; aggN = mean_n(z) = [a_pn | a_nn]
    agg_csr<false><<<gA, 256, 0, stream>>>(offp, eidp, invp, out, nullptr, aggP);
    agg_csr<false><<<gA, 256, 0, stream>>>(offn, eidn, invn, out, nullptr, aggN);

    // out_pos = relu(concat(a_pp, a_nn) @ wpl + zp @ wpr + bpr)
    gemm2<64, false><<<gG, 256, 0, stream>>>(aggP, 0, aggN, 64, wpl,
                                             out, nullptr, 0, wpr, bpr, out, 0);
    // out_neg = relu(concat(a_np, a_pn) @ wnl + zn @ wnr + bnr)
    gemm2<64, false><<<gG, 256, 0, stream>>>(aggP, 64, aggN, 0, wnl,
                                             out, nullptr, 64, wnr, bnr, out, 64);
  }
}